// Round 2
// 90.960 us; speedup vs baseline: 1.1336x; 1.1336x over previous
//
#include <hip/hip_runtime.h>
#include <math.h>

// B=64, IN=1024, output_size=1024, D_MODEL=64, X_KS=Y_KS=32, HIDDEN=256
constexpr int B    = 64;
constexpr int IN   = 1024;
constexpr int OUTN = 1024;
constexpr int H    = 256;

#define LN10000 9.210340371976184f
#define TWO_LOG2E 2.8853900817779268f   // 2*log2(e); exp(2x) = exp2(x*TWO_LOG2E)

__device__ __forceinline__ float fast_tanh(float x) {
    // tanh(x) = 1 - 2/(e^{2x}+1); error budget is huge (absmax thresh 1.47)
    x = fminf(fmaxf(x, -15.0f), 15.0f);
    float e = __builtin_amdgcn_exp2f(x * TWO_LOG2E);
    return 1.0f - 2.0f * __builtin_amdgcn_rcpf(e + 1.0f);
}

// ===========================================================================
// PATH A (needs 164 KB workspace): k0_tables + k1_new + k2_new
// ===========================================================================

// ---------------------------------------------------------------------------
// K0: 96 blocks = (table in [0,3), p in [0,32)), 256 threads = c.
//   PA[p][c]  = b1[c]  + sum_d pe(p)[d] * W1[d][c]        (pe_x rows 0..63)
//   PY[p][c]  =          sum_d pe(p)[d] * W1[64+d][c]     (pe_y rows 64..127)
//   HPE[t][c] = bb1[c] + sum_d pe(t)[d] * Wb1[32+d][c]    (bias-hypernet pe)
// All trig + all b-redundant matmul work lives here.
// ---------------------------------------------------------------------------
__global__ void __launch_bounds__(256) k0_tables(const float* __restrict__ W1,
                                                 const float* __restrict__ b1,
                                                 const float* __restrict__ Wb1,
                                                 const float* __restrict__ bb1,
                                                 float* __restrict__ PA,
                                                 float* __restrict__ PY,
                                                 float* __restrict__ HPE) {
    __shared__ float pe[64];
    const int blk = blockIdx.x, tid = threadIdx.x;
    const int p = blk & 31, table = blk >> 5;
    if (tid < 32) {
        float freq = expf(-(2.0f * (float)tid / 64.0f) * LN10000);
        float a = (float)p * freq;
        pe[2 * tid]     = sinf(a);
        pe[2 * tid + 1] = cosf(a);
    }
    __syncthreads();
    const float* src; float bias; float* dst;
    if (table == 0)      { src = W1;           bias = b1[tid];  dst = PA;  }
    else if (table == 1) { src = W1 + 64 * H;  bias = 0.0f;     dst = PY;  }
    else                 { src = Wb1 + 32 * H; bias = bb1[tid]; dst = HPE; }
    float acc = bias;
    #pragma unroll 16
    for (int d = 0; d < 64; ++d) acc += pe[d] * src[d * H + tid];   // coalesced 1KB/row
    dst[p * H + tid] = acc;
}

// ---------------------------------------------------------------------------
// K1: 256 blocks = (b, cq), 1024 threads (16 waves -> 4/SIMD, 2x old occupancy).
// Per thread only ~7 coalesced global loads (vs 160 serialized before):
// stage x row, W1 x-chunk slice, PY slice; compute Q in-block (64 FMA/thread);
// then the tanh core. cq==0 wave 0 emits S[b] via shuffle.
// ---------------------------------------------------------------------------
__global__ void __launch_bounds__(1024, 4) k1_new(const float* __restrict__ x,
                                                  const float* __restrict__ W1,
                                                  const float* __restrict__ PA,
                                                  const float* __restrict__ PY,
                                                  float* __restrict__ v,
                                                  float* __restrict__ S) {
    __shared__ float xs[1024];
    __shared__ float w1s[2048];   // W1[128+k][c0+cl], k<32, cl<64
    __shared__ float As[2048];    // PA + Q
    __shared__ float Ps[2048];    // PY slice
    __shared__ float red[1024];
    const int blk = blockIdx.x, tid = threadIdx.x;
    const int b = blk >> 2, cq = blk & 3, c0 = cq * 64;
    const int cl = tid & 63, jg = tid >> 6;   // jg in [0,16)

    xs[tid] = x[b * IN + tid];
    #pragma unroll
    for (int i = 0; i < 2; ++i) {
        const int idx = i * 1024 + tid;
        const int p = idx >> 6, c = idx & 63;
        w1s[idx] = W1[(128 + p) * H + c0 + c];
        Ps[idx]  = PY[p * H + c0 + c];
    }
    __syncthreads();

    if (cq == 0 && tid < 64) {        // S[b]: one wave, shuffle reduce
        float s = 0.0f;
        #pragma unroll
        for (int i = 0; i < 16; ++i) s += xs[tid + i * 64];
        #pragma unroll
        for (int off = 32; off > 0; off >>= 1) s += __shfl_xor(s, off, 64);
        if (tid == 0) S[b] = s;
    }

    // As[jx][cl] = PA[jx][c] + sum_k xs[jx*32+k]*w1s[k][cl]
    #pragma unroll
    for (int r = 0; r < 2; ++r) {
        const int jx = jg * 2 + r;
        float q = PA[jx * H + c0 + cl];           // coalesced
        #pragma unroll 8
        for (int k = 0; k < 32; ++k)
            q += xs[jx * 32 + k] * w1s[k * 64 + cl];   // broadcast x stride-1 w1s
        As[jx * 64 + cl] = q;
    }
    __syncthreads();

    float Areg[32];
    #pragma unroll
    for (int jx = 0; jx < 32; ++jx) Areg[jx] = As[jx * 64 + cl];
    float acc = 0.0f;
    #pragma unroll
    for (int r = 0; r < 2; ++r) {
        const int jy = jg * 2 + r;
        const float pyv = Ps[jy * 64 + cl];
        const float4* xr = (const float4*)(xs + jy * 32);
        #pragma unroll
        for (int q8 = 0; q8 < 8; ++q8) {
            float4 xv = xr[q8];
            acc += xv.x * fast_tanh(Areg[q8 * 4 + 0] + pyv);
            acc += xv.y * fast_tanh(Areg[q8 * 4 + 1] + pyv);
            acc += xv.z * fast_tanh(Areg[q8 * 4 + 2] + pyv);
            acc += xv.w * fast_tanh(Areg[q8 * 4 + 3] + pyv);
        }
    }
    red[tid] = acc;                   // layout jg*64 + cl == tid
    __syncthreads();
    if (tid < 64) {
        float s = 0.0f;
        #pragma unroll
        for (int g = 0; g < 16; ++g) s += red[g * 64 + tid];
        v[b * H + c0 + tid] = s;
    }
}

// ---------------------------------------------------------------------------
// K2: 256 blocks = (og, bg), 1024 threads (16 waves -> 4/SIMD, 4x old occ).
// h = tid>>8 in [0,4): 4-way c-split of all three serial reductions.
// Wb2 staged in LDS; HPE loaded (pe half of bias hypernet hoisted to k0).
// ---------------------------------------------------------------------------
__global__ void __launch_bounds__(1024) k2_new(const float* __restrict__ v,
                                               const float* __restrict__ S,
                                               const float* __restrict__ W2,
                                               const float* __restrict__ b2,
                                               const float* __restrict__ Wb1,
                                               const float* __restrict__ HPE,
                                               const float* __restrict__ Wb2,
                                               const float* __restrict__ bb2,
                                               float* __restrict__ out) {
    __shared__ float vsh[2048];      // v rows for 8 samples
    __shared__ float hpe[256];       // HPE[og][:]
    __shared__ float osp[1024];      // phase-1 partials (4 quarters)
    __shared__ float os[256];        // out-tile (pre-bias)
    __shared__ float hbs[2048];      // tanh activations
    __shared__ float Wb2s[8192];     // staged Wb2
    __shared__ float bp[1024];       // phase-3 partials
    __shared__ float Ssh[8];
    const int blk = blockIdx.x, tid = threadIdx.x;
    const int og = blk & 31, bg = blk >> 5, b0 = bg * 8;
    const int h = tid >> 8, u = tid & 255, bl = u >> 5, ol = u & 31;

    ((float2*)vsh)[tid] = ((const float2*)(v + b0 * H))[tid];
    #pragma unroll
    for (int i = 0; i < 2; ++i)
        ((float4*)Wb2s)[i * 1024 + tid] = ((const float4*)Wb2)[i * 1024 + tid];
    if (tid < 256) hpe[tid] = HPE[og * H + tid];
    if (tid < 8) Ssh[tid] = S[b0 + tid];
    __syncthreads();

    const int o = og * 32 + ol;
    // phase 1: os[bl][ol] = S*b2 + v[b]·W2[:,o]  (c-quarter per h)
    {
        float acc = (h == 0) ? Ssh[bl] * b2[o] : 0.0f;
        const float4* vr = (const float4*)(vsh + bl * H + h * 64);
        const int cb = h * 64;
        #pragma unroll
        for (int c4 = 0; c4 < 16; ++c4) {
            float4 v4 = vr[c4];
            const int c = cb + c4 * 4;
            acc += v4.x * W2[(c + 0) * OUTN + o];
            acc += v4.y * W2[(c + 1) * OUTN + o];
            acc += v4.z * W2[(c + 2) * OUTN + o];
            acc += v4.w * W2[(c + 3) * OUTN + o];
        }
        osp[h * 256 + u] = acc;
    }
    __syncthreads();
    if (tid < 256)
        os[tid] = osp[tid] + osp[256 + tid] + osp[512 + tid] + osp[768 + tid];
    __syncthreads();
    // phase 2: hb[bl][c] = tanh(hpe[c] + sum_k os[bl][k]*Wb1[k][c]),
    // thread covers c = h*64 + {0,32} + ol
    {
        float a0 = hpe[h * 64 + ol];
        float a1 = hpe[h * 64 + 32 + ol];
        #pragma unroll 8
        for (int k = 0; k < 32; ++k) {
            const float xo = os[bl * 32 + k];
            const float* wr = Wb1 + k * H + h * 64 + ol;
            a0 += xo * wr[0];
            a1 += xo * wr[32];
        }
        hbs[bl * H + h * 64 + ol]      = fast_tanh(a0);
        hbs[bl * H + h * 64 + 32 + ol] = fast_tanh(a1);
    }
    __syncthreads();
    // phase 3: bias = bb2 + hb·Wb2  (c-quarter per h, Wb2 from LDS)
    {
        float bias = (h == 0) ? bb2[ol] : 0.0f;
        const float4* hr = (const float4*)(hbs + bl * H + h * 64);
        const int cb = h * 64;
        #pragma unroll
        for (int c4 = 0; c4 < 16; ++c4) {
            float4 h4 = hr[c4];
            const int c = cb + c4 * 4;
            bias += h4.x * Wb2s[(c + 0) * 32 + ol];
            bias += h4.y * Wb2s[(c + 1) * 32 + ol];
            bias += h4.z * Wb2s[(c + 2) * 32 + ol];
            bias += h4.w * Wb2s[(c + 3) * 32 + ol];
        }
        bp[h * 256 + u] = bias;
    }
    __syncthreads();
    if (tid < 256) {
        out[(b0 + (tid >> 5)) * OUTN + og * 32 + (tid & 31)] =
            os[tid] + bp[tid] + bp[256 + tid] + bp[512 + tid] + bp[768 + tid];
    }
}

// ===========================================================================
// PATH B (fallback, 65.8 KB workspace): verbatim proven round-0 kernels
// ===========================================================================
__global__ void __launch_bounds__(512) k1_old(const float* __restrict__ x,
                                              const float* __restrict__ W1,
                                              const float* __restrict__ b1,
                                              float* __restrict__ v,
                                              float* __restrict__ S) {
    __shared__ float xs[1024];
    __shared__ float pe[32 * 64];
    __shared__ float A[32 * 64];
    __shared__ float Pyl[32 * 64];
    __shared__ float red[512];
    const int blk = blockIdx.x, tid = threadIdx.x;
    const int b = blk >> 2, cq = blk & 3, c0 = cq * 64;

    ((float2*)xs)[tid] = ((const float2*)(x + b * IN))[tid];
    #pragma unroll
    for (int r = 0; r < 2; ++r) {
        const int idx = r * 512 + tid;
        const int p = idx >> 5, i = idx & 31;
        float freq = expf(-(2.0f * (float)i / 64.0f) * LN10000);
        float a = (float)p * freq;
        pe[p * 64 + 2 * i]     = sinf(a);
        pe[p * 64 + 2 * i + 1] = cosf(a);
    }
    __syncthreads();

    if (cq == 0) {
        red[tid] = xs[tid] + xs[tid + 512];
        __syncthreads();
        for (int s = 256; s > 0; s >>= 1) {
            if (tid < s) red[tid] += red[tid + s];
            __syncthreads();
        }
        if (tid == 0) S[b] = red[0];
    }

    const int cl = tid & 63, jg = tid >> 6, j0 = jg * 4;
    const float b1v = b1[c0 + cl];
    float accA[4], accP[4];
    #pragma unroll
    for (int r = 0; r < 4; ++r) { accA[r] = b1v; accP[r] = 0.0f; }
    for (int d = 0; d < 64; ++d) {
        const float wx = W1[d * H + c0 + cl];
        const float wy = W1[(64 + d) * H + c0 + cl];
        #pragma unroll
        for (int r = 0; r < 4; ++r) {
            const float p = pe[(j0 + r) * 64 + d];
            accA[r] += p * wx;
            accP[r] += p * wy;
        }
    }
    for (int k = 0; k < 32; ++k) {
        const float wq = W1[(128 + k) * H + c0 + cl];
        #pragma unroll
        for (int r = 0; r < 4; ++r) accA[r] += xs[(j0 + r) * 32 + k] * wq;
    }
    #pragma unroll
    for (int r = 0; r < 4; ++r) {
        A[(j0 + r) * 64 + cl]   = accA[r];
        Pyl[(j0 + r) * 64 + cl] = accP[r];
    }
    __syncthreads();

    float Areg[32];
    #pragma unroll
    for (int jx = 0; jx < 32; ++jx) Areg[jx] = A[jx * 64 + cl];
    float acc = 0.0f;
    for (int r = 0; r < 4; ++r) {
        const int jy = j0 + r;
        const float pyv = Pyl[jy * 64 + cl];
        const float4* xr = (const float4*)(xs + jy * 32);
        #pragma unroll
        for (int q = 0; q < 8; ++q) {
            float4 xv = xr[q];
            acc += xv.x * fast_tanh(Areg[q * 4 + 0] + pyv);
            acc += xv.y * fast_tanh(Areg[q * 4 + 1] + pyv);
            acc += xv.z * fast_tanh(Areg[q * 4 + 2] + pyv);
            acc += xv.w * fast_tanh(Areg[q * 4 + 3] + pyv);
        }
    }
    red[tid] = acc;
    __syncthreads();
    if (tid < 64) {
        float s = 0.0f;
        #pragma unroll
        for (int g = 0; g < 8; ++g) s += red[g * 64 + tid];
        v[b * H + c0 + tid] = s;
    }
}

__global__ void __launch_bounds__(256) k2_old(const float* __restrict__ v,
                                              const float* __restrict__ S,
                                              const float* __restrict__ W2,
                                              const float* __restrict__ b2,
                                              const float* __restrict__ Wb1,
                                              const float* __restrict__ bb1,
                                              const float* __restrict__ Wb2,
                                              const float* __restrict__ bb2,
                                              float* __restrict__ out) {
    __shared__ float vsh[8 * 256];
    __shared__ float pes[64];
    __shared__ float hpe[256];
    __shared__ float os[8 * 32];
    __shared__ float hbs[8 * 256];
    __shared__ float Ssh[8];
    const int blk = blockIdx.x, tid = threadIdx.x;
    const int og = blk & 31, bg = blk >> 5;
    const int bl = tid >> 5, ol = tid & 31;
    const int b0 = bg * 8;

    ((float4*)vsh)[tid]       = ((const float4*)(v + b0 * H))[tid];
    ((float4*)vsh)[tid + 256] = ((const float4*)(v + b0 * H))[tid + 256];
    if (tid < 8) Ssh[tid] = S[b0 + tid];
    if (tid >= 64 && tid < 96) {
        const int i = tid - 64;
        float freq = expf(-(2.0f * (float)i / 64.0f) * LN10000);
        float a = (float)og * freq;
        pes[2 * i]     = sinf(a);
        pes[2 * i + 1] = cosf(a);
    }
    __syncthreads();

    {
        float a = bb1[tid];
        #pragma unroll 8
        for (int d = 0; d < 64; ++d)
            a += pes[d] * Wb1[(32 + d) * H + tid];
        hpe[tid] = a;
    }

    const int o = og * 32 + ol;
    float acc = Ssh[bl] * b2[o];
    const float4* vr = (const float4*)(vsh + bl * 256);
    #pragma unroll 4
    for (int c4 = 0; c4 < 64; ++c4) {
        float4 v4 = vr[c4];
        acc += v4.x * W2[(c4 * 4 + 0) * OUTN + o];
        acc += v4.y * W2[(c4 * 4 + 1) * OUTN + o];
        acc += v4.z * W2[(c4 * 4 + 2) * OUTN + o];
        acc += v4.w * W2[(c4 * 4 + 3) * OUTN + o];
    }
    os[bl * 32 + ol] = acc;
    __syncthreads();

    {
        const int c8 = ol * 8;
        float a[8];
        #pragma unroll
        for (int j = 0; j < 8; ++j) a[j] = hpe[c8 + j];
        #pragma unroll 4
        for (int k = 0; k < 32; ++k) {
            const float xo = os[bl * 32 + k];
            const float4* wr = (const float4*)(Wb1 + k * H + c8);
            float4 w0 = wr[0], w1 = wr[1];
            a[0] += xo * w0.x; a[1] += xo * w0.y; a[2] += xo * w0.z; a[3] += xo * w0.w;
            a[4] += xo * w1.x; a[5] += xo * w1.y; a[6] += xo * w1.z; a[7] += xo * w1.w;
        }
        #pragma unroll
        for (int j = 0; j < 8; ++j) hbs[bl * 256 + c8 + j] = fast_tanh(a[j]);
    }
    __syncthreads();

    {
        float bias = bb2[ol];
        const float4* hr = (const float4*)(hbs + bl * 256);
        #pragma unroll 4
        for (int c4 = 0; c4 < 64; ++c4) {
            float4 h4 = hr[c4];
            bias += h4.x * Wb2[(c4 * 4 + 0) * 32 + ol];
            bias += h4.y * Wb2[(c4 * 4 + 1) * 32 + ol];
            bias += h4.z * Wb2[(c4 * 4 + 2) * 32 + ol];
            bias += h4.w * Wb2[(c4 * 4 + 3) * 32 + ol];
        }
        out[(b0 + bl) * OUTN + og * 32 + ol] = os[bl * 32 + ol] + bias;
    }
}

// ---------------------------------------------------------------------------
extern "C" void kernel_launch(void* const* d_in, const int* in_sizes, int n_in,
                              void* d_out, int out_size, void* d_ws, size_t ws_size,
                              hipStream_t stream) {
    const float* x   = (const float*)d_in[0];
    // d_in[1] = output_size (fixed 1024)
    const float* W1  = (const float*)d_in[2];
    const float* b1  = (const float*)d_in[3];
    const float* W2  = (const float*)d_in[4];
    const float* b2  = (const float*)d_in[5];
    const float* Wb1 = (const float*)d_in[6];
    const float* bb1 = (const float*)d_in[7];
    const float* Wb2 = (const float*)d_in[8];
    const float* bb2 = (const float*)d_in[9];
    float* out = (float*)d_out;

    float* v = (float*)d_ws;                         // B*H
    float* S = v + B * H;                            // B

    const size_t needA = (size_t)(B * H + B + 3 * 32 * H) * sizeof(float);
    if (ws_size >= needA) {
        float* PA  = S + B;                          // 32*H
        float* PY  = PA + 32 * H;                    // 32*H
        float* HPE = PY + 32 * H;                    // 32*H
        hipLaunchKernelGGL(k0_tables, dim3(96),  dim3(256),  0, stream,
                           W1, b1, Wb1, bb1, PA, PY, HPE);
        hipLaunchKernelGGL(k1_new,    dim3(B*4), dim3(1024), 0, stream,
                           x, W1, PA, PY, v, S);
        hipLaunchKernelGGL(k2_new,    dim3(256), dim3(1024), 0, stream,
                           v, S, W2, b2, Wb1, HPE, Wb2, bb2, out);
    } else {
        hipLaunchKernelGGL(k1_old, dim3(B*4), dim3(512), 0, stream, x, W1, b1, v, S);
        hipLaunchKernelGGL(k2_old, dim3(256), dim3(256), 0, stream,
                           v, S, W2, b2, Wb1, bb1, Wb2, bb2, out);
    }
}